// Round 1
// baseline (259.355 us; speedup 1.0000x reference)
//
#include <hip/hip_runtime.h>
#include <cstddef>

#define FCH   32
#define CH    192
#define CWID  640
#define IMG_H 384
#define IMG_W 1280
#define TW    128
#define GROWS 224   // TW + 96
#define NDISP 96

// XOR-swizzled LDS float index for a [row][32-float] tile read/written as float4.
// Row stride = 128B = all 32 banks, so bank depends only on the 16B chunk; XOR the
// chunk with (row>>2)&7 so lanes whose row stride is 4 sweep all 8 chunk positions.
__device__ __forceinline__ int swz(int row, int c4) {
  return row * 32 + (((c4 >> 2) ^ ((row >> 2) & 7)) << 2);
}

// ---------------- Kernel 1: 3x3 stride-2 SAME conv + bias + ReLU ----------------
// Input x = concat(xl, xr) along batch (4 images). XLA SAME for in=384/1280, k=3, s=2:
// pad_lo = 0, pad_hi = 1 -> in_row = 2*oh + kh, skip if >= in extent.
__global__ __launch_bounds__(256)
void conv_relu_kernel(const float* __restrict__ xl, const float* __restrict__ xr,
                      const float* __restrict__ Wt, const float* __restrict__ bias,
                      float* __restrict__ Fc) {
  __shared__ float wl[864];
  __shared__ float bl[32];
  const int tid = threadIdx.x;
  for (int t = tid; t < 864; t += 256) wl[t] = Wt[t];
  if (tid < 32) bl[tid] = bias[tid];
  __syncthreads();

  const int g  = blockIdx.x * 256 + tid;   // [0, 4*192*640)
  const int ow = g % CWID;
  const int t2 = g / CWID;
  const int oh = t2 % CH;
  const int bb = t2 / CH;
  const float* src = (bb < 2) ? (xl + (size_t)bb * IMG_H * IMG_W * 3)
                              : (xr + (size_t)(bb - 2) * IMG_H * IMG_W * 3);
  float acc[32];
  #pragma unroll
  for (int c = 0; c < 32; ++c) acc[c] = bl[c];

  #pragma unroll
  for (int kh = 0; kh < 3; ++kh) {
    const int ir = oh * 2 + kh;
    if (ir >= IMG_H) continue;
    #pragma unroll
    for (int kw = 0; kw < 3; ++kw) {
      const int ic = ow * 2 + kw;
      if (ic >= IMG_W) continue;
      const float* px = src + ((size_t)ir * IMG_W + ic) * 3;
      #pragma unroll
      for (int ci = 0; ci < 3; ++ci) {
        const float v = px[ci];
        const float* wp = &wl[((kh * 3 + kw) * 3 + ci) * 32];
        #pragma unroll
        for (int c8 = 0; c8 < 8; ++c8) {
          const float4 w4 = *(const float4*)(wp + c8 * 4);
          acc[c8 * 4 + 0] = fmaf(v, w4.x, acc[c8 * 4 + 0]);
          acc[c8 * 4 + 1] = fmaf(v, w4.y, acc[c8 * 4 + 1]);
          acc[c8 * 4 + 2] = fmaf(v, w4.z, acc[c8 * 4 + 2]);
          acc[c8 * 4 + 3] = fmaf(v, w4.w, acc[c8 * 4 + 3]);
        }
      }
    }
  }
  float* dst = Fc + (size_t)g * 32;
  #pragma unroll
  for (int c8 = 0; c8 < 8; ++c8) {
    float4 o;
    o.x = fmaxf(acc[c8 * 4 + 0], 0.f);
    o.y = fmaxf(acc[c8 * 4 + 1], 0.f);
    o.z = fmaxf(acc[c8 * 4 + 2], 0.f);
    o.w = fmaxf(acc[c8 * 4 + 3], 0.f);
    *(float4*)(dst + c8 * 4) = o;
  }
}

// ------- Kernel 2: fused 2x bilinear upsample + cost volume + soft-argmin -------
// One block per (b, h, 128-wide w tile). d in [0,96); k = 95-d; j = i + k indexes
// the fr tile which starts at up-col (w0 - 95) mod 1280.
__global__ __launch_bounds__(256)
void disparity_fused_kernel(const float* __restrict__ Fc, float* __restrict__ out) {
  __shared__ float flT[TW * 32];      // 16 KB, swizzled
  __shared__ float gT[GROWS * 32];    // 28 KB, swizzled
  __shared__ float As[TW];
  __shared__ float Bs[GROWS];
  __shared__ float mnA[8 * TW];       // [kgroup][i]
  __shared__ float mxA[8 * TW];
  __shared__ float gmn[TW];
  __shared__ float gmx[TW];
  __shared__ float psw[8 * TW];       // [kgroup][i]
  __shared__ float psdw[8 * TW];

  const int tid = threadIdx.x;
  const int w0  = blockIdx.x * TW;
  const int h   = blockIdx.y;
  const int bz  = blockIdx.z;

  // vertical bilinear params (half-pixel, clamped == jax.image.resize bilinear 2x)
  const int hk = h >> 1;
  int r0, r1; float wv0, wv1;
  if (h & 1) { r0 = hk; r1 = (hk + 1 > CH - 1) ? CH - 1 : hk + 1; wv0 = 0.75f; wv1 = 0.25f; }
  else       { r0 = (hk - 1 < 0) ? 0 : hk - 1; r1 = hk;           wv0 = 0.25f; wv1 = 0.75f; }

  // ---- Phase 1: stage upsampled fl (128 cols) and fr (224 cols) rows into LDS ----
  for (int task = tid; task < (TW + GROWS) * 8; task += 256) {
    const bool isfl = task < TW * 8;
    const int local = isfl ? task : task - TW * 8;
    const int row = local >> 3;
    const int c4  = (local & 7) << 2;
    const int wup = isfl ? (w0 + row) : (w0 - 95 + row + IMG_W) % IMG_W;
    const int m   = wup >> 1;
    const int odd = wup & 1;
    int m0 = odd ? m : m - 1;
    int m1 = odd ? m + 1 : m;
    const float wh0 = odd ? 0.75f : 0.25f;
    const float wh1 = odd ? 0.25f : 0.75f;
    if (m0 < 0) m0 = 0;
    if (m1 > CWID - 1) m1 = CWID - 1;
    const int bb = isfl ? bz : bz + 2;
    const size_t rb0 = ((size_t)bb * CH + r0) * CWID;
    const size_t rb1 = ((size_t)bb * CH + r1) * CWID;
    const float4 a00 = *(const float4*)(Fc + (rb0 + m0) * 32 + c4);
    const float4 a01 = *(const float4*)(Fc + (rb0 + m1) * 32 + c4);
    const float4 a10 = *(const float4*)(Fc + (rb1 + m0) * 32 + c4);
    const float4 a11 = *(const float4*)(Fc + (rb1 + m1) * 32 + c4);
    float4 v;
    v.x = wv0 * (wh0 * a00.x + wh1 * a01.x) + wv1 * (wh0 * a10.x + wh1 * a11.x);
    v.y = wv0 * (wh0 * a00.y + wh1 * a01.y) + wv1 * (wh0 * a10.y + wh1 * a11.y);
    v.z = wv0 * (wh0 * a00.z + wh1 * a01.z) + wv1 * (wh0 * a10.z + wh1 * a11.z);
    v.w = wv0 * (wh0 * a00.w + wh1 * a01.w) + wv1 * (wh0 * a10.w + wh1 * a11.w);
    float* dst = (isfl ? flT : gT) + swz(row, c4);
    *(float4*)dst = v;
  }
  __syncthreads();

  // ---- Phase A: squared norms A[i], B[j] ----
  for (int task = tid; task < TW + GROWS; task += 256) {
    const bool isfl = task < TW;
    const int row = isfl ? task : task - TW;
    const float* buf = isfl ? flT : gT;
    float s = 0.f;
    #pragma unroll
    for (int c = 0; c < 32; c += 4) {
      const float4 v = *(const float4*)(buf + swz(row, c));
      s += v.x * v.x + v.y * v.y + v.z * v.z + v.w * v.w;
    }
    if (isfl) As[row] = s; else Bs[row] = s;
  }
  __syncthreads();

  // ---- Phase 2: banded correlation, 4i x 12k register tile per thread ----
  const int i0 = (tid & 31) * 4;   // 32 i-groups
  const int kg = tid >> 5;         // 8 k-groups
  const int k0 = kg * 12;
  float acc[4][12];
  #pragma unroll
  for (int a = 0; a < 4; ++a)
    #pragma unroll
    for (int b = 0; b < 12; ++b) acc[a][b] = 0.f;

  #pragma unroll
  for (int c = 0; c < 32; c += 4) {
    float4 fv[4];
    #pragma unroll
    for (int ii = 0; ii < 4; ++ii) fv[ii] = *(const float4*)(flT + swz(i0 + ii, c));
    float4 gv[15];
    #pragma unroll
    for (int jj = 0; jj < 15; ++jj) gv[jj] = *(const float4*)(gT + swz(i0 + k0 + jj, c));
    #pragma unroll
    for (int ii = 0; ii < 4; ++ii) {
      #pragma unroll
      for (int kk = 0; kk < 12; ++kk) {
        const float4 a = fv[ii];
        const float4 g = gv[ii + kk];
        acc[ii][kk] += a.x * g.x + a.y * g.y + a.z * g.z + a.w * g.w;
      }
    }
  }

  // finalize cost (in regs) + per-thread min/max
  #pragma unroll
  for (int ii = 0; ii < 4; ++ii) {
    const float Ai = As[i0 + ii];
    float mn = 3.0e38f, mx = -3.0e38f;
    #pragma unroll
    for (int kk = 0; kk < 12; ++kk) {
      const float cv = Ai + Bs[i0 + ii + k0 + kk] - 2.f * acc[ii][kk];
      acc[ii][kk] = cv;
      mn = fminf(mn, cv);
      mx = fmaxf(mx, cv);
    }
    mnA[kg * TW + (i0 + ii)] = mn;
    mxA[kg * TW + (i0 + ii)] = mx;
  }
  __syncthreads();

  // ---- Phase 3a: reduce min/max over the 8 k-groups per pixel ----
  if (tid < TW) {
    float mn = mnA[tid], mx = mxA[tid];
    #pragma unroll
    for (int q = 1; q < 8; ++q) {
      mn = fminf(mn, mnA[q * TW + tid]);
      mx = fmaxf(mx, mxA[q * TW + tid]);
    }
    gmn[tid] = mn;
    gmx[tid] = mx;
  }
  __syncthreads();

  // ---- Phase 3b: partial softmax sums (cost still live in registers) ----
  #pragma unroll
  for (int ii = 0; ii < 4; ++ii) {
    const int i = i0 + ii;
    const float alpha = 177.0f / gmx[i];
    const float mn = gmn[i];
    float sw = 0.f, sdw = 0.f;
    #pragma unroll
    for (int kk = 0; kk < 12; ++kk) {
      const float wgt = __expf(alpha * (mn - acc[ii][kk]));  // in (0,1], stable
      sw += wgt;
      sdw += (float)(95 - (k0 + kk)) * wgt;                   // d = 95 - k
    }
    psw[kg * TW + i]  = sw;
    psdw[kg * TW + i] = sdw;
  }
  __syncthreads();

  // ---- Phase 3c: final reduce + soft-argmin write ----
  if (tid < TW) {
    float sw = 0.f, sdw = 0.f;
    #pragma unroll
    for (int q = 0; q < 8; ++q) {
      sw  += psw[q * TW + tid];
      sdw += psdw[q * TW + tid];
    }
    out[((size_t)bz * IMG_H + h) * IMG_W + w0 + tid] = sdw / sw;
  }
}

extern "C" void kernel_launch(void* const* d_in, const int* in_sizes, int n_in,
                              void* d_out, int out_size, void* d_ws, size_t ws_size,
                              hipStream_t stream) {
  (void)in_sizes; (void)n_in; (void)out_size; (void)ws_size;
  const float* xl   = (const float*)d_in[0];
  const float* xr   = (const float*)d_in[1];
  const float* Wt   = (const float*)d_in[2];
  const float* bias = (const float*)d_in[3];
  float* Fc  = (float*)d_ws;        // conv features [4,192,640,32] f32 = 62.9 MB
  float* out = (float*)d_out;       // [2,384,1280] f32

  hipLaunchKernelGGL(conv_relu_kernel, dim3(1920), dim3(256), 0, stream,
                     xl, xr, Wt, bias, Fc);
  hipLaunchKernelGGL(disparity_fused_kernel, dim3(IMG_W / TW, IMG_H, 2), dim3(256), 0, stream,
                     Fc, out);
}

// Round 2
// 210.416 us; speedup vs baseline: 1.2326x; 1.2326x over previous
//
#include <hip/hip_runtime.h>
#include <cstddef>

#define FCH   32
#define CH    192
#define CWID  640
#define IMG_H 384
#define IMG_W 1280
#define TW    128
#define GROWS 224   // TW + 96
#define NDISP 96

// XOR-swizzled LDS float index for a [row][32-float] tile accessed as float4.
// Row stride = 128B = all 32 banks, so bank depends only on the 16B chunk; XOR the
// chunk with (row>>2)&7 so lanes striding rows sweep all 8 chunk positions.
__device__ __forceinline__ int swz(int row, int c4) {
  return row * 32 + (((c4 >> 2) ^ ((row >> 2) & 7)) << 2);
}

// ---------------- Kernel 1: 3x3 stride-2 SAME conv + bias + ReLU ----------------
__global__ __launch_bounds__(256)
void conv_relu_kernel(const float* __restrict__ xl, const float* __restrict__ xr,
                      const float* __restrict__ Wt, const float* __restrict__ bias,
                      float* __restrict__ Fc) {
  __shared__ float wl[864];
  __shared__ float bl[32];
  const int tid = threadIdx.x;
  for (int t = tid; t < 864; t += 256) wl[t] = Wt[t];
  if (tid < 32) bl[tid] = bias[tid];
  __syncthreads();

  const int g  = blockIdx.x * 256 + tid;   // [0, 4*192*640)
  const int ow = g % CWID;
  const int t2 = g / CWID;
  const int oh = t2 % CH;
  const int bb = t2 / CH;
  const float* src = (bb < 2) ? (xl + (size_t)bb * IMG_H * IMG_W * 3)
                              : (xr + (size_t)(bb - 2) * IMG_H * IMG_W * 3);
  float acc[32];
  #pragma unroll
  for (int c = 0; c < 32; ++c) acc[c] = bl[c];

  #pragma unroll
  for (int kh = 0; kh < 3; ++kh) {
    const int ir = oh * 2 + kh;
    if (ir >= IMG_H) continue;
    #pragma unroll
    for (int kw = 0; kw < 3; ++kw) {
      const int ic = ow * 2 + kw;
      if (ic >= IMG_W) continue;
      const float* px = src + ((size_t)ir * IMG_W + ic) * 3;
      #pragma unroll
      for (int ci = 0; ci < 3; ++ci) {
        const float v = px[ci];
        const float* wp = &wl[((kh * 3 + kw) * 3 + ci) * 32];
        #pragma unroll
        for (int c8 = 0; c8 < 8; ++c8) {
          const float4 w4 = *(const float4*)(wp + c8 * 4);
          acc[c8 * 4 + 0] = fmaf(v, w4.x, acc[c8 * 4 + 0]);
          acc[c8 * 4 + 1] = fmaf(v, w4.y, acc[c8 * 4 + 1]);
          acc[c8 * 4 + 2] = fmaf(v, w4.z, acc[c8 * 4 + 2]);
          acc[c8 * 4 + 3] = fmaf(v, w4.w, acc[c8 * 4 + 3]);
        }
      }
    }
  }
  float* dst = Fc + (size_t)g * 32;
  #pragma unroll
  for (int c8 = 0; c8 < 8; ++c8) {
    float4 o;
    o.x = fmaxf(acc[c8 * 4 + 0], 0.f);
    o.y = fmaxf(acc[c8 * 4 + 1], 0.f);
    o.z = fmaxf(acc[c8 * 4 + 2], 0.f);
    o.w = fmaxf(acc[c8 * 4 + 3], 0.f);
    *(float4*)(dst + c8 * 4) = o;
  }
}

// ------- Kernel 2: fused 2x bilinear upsample + cost volume + soft-argmin -------
// One block per (b, h, 128-wide w tile). d in [0,96); k = 95-d; j = i + k indexes
// the fr tile which starts at up-col (w0 - 95) mod 1280.
// Register discipline: acc 4x12 (48) + fv float4[4] (16) + ONE sliding g (4) +
// 19 precomputed byte-addresses; per-load address = 1 v_xor_b32 with literal.
// LDS 47.5KB (phase-3 scratch aliased onto dead flT) -> 3 blocks/CU.
__global__ __launch_bounds__(256, 3)
void disparity_fused_kernel(const float* __restrict__ Fc, float* __restrict__ out) {
  __shared__ float flT[TW * 32];      // 16 KB, swizzled; reused as phase-3 scratch
  __shared__ float gT[GROWS * 32];    // 28 KB, swizzled
  __shared__ float As[TW];
  __shared__ float Bs[GROWS];
  __shared__ float gmn[TW];
  __shared__ float gmx[TW];
  // phase-3 scratch aliased onto flT (4096 floats = 4 x 1024)
  float* const mnA  = flT;            // [8][TW]
  float* const mxA  = flT + 1024;
  float* const psw  = flT + 2048;
  float* const psdw = flT + 3072;

  const int tid = threadIdx.x;
  const int w0  = blockIdx.x * TW;
  const int h   = blockIdx.y;
  const int bz  = blockIdx.z;

  // vertical bilinear params (half-pixel, clamped == jax.image.resize bilinear 2x)
  const int hk = h >> 1;
  int r0, r1; float wv0, wv1;
  if (h & 1) { r0 = hk; r1 = (hk + 1 > CH - 1) ? CH - 1 : hk + 1; wv0 = 0.75f; wv1 = 0.25f; }
  else       { r0 = (hk - 1 < 0) ? 0 : hk - 1; r1 = hk;           wv0 = 0.25f; wv1 = 0.75f; }

  // ---- Phase 1: stage upsampled fl (128 cols) and fr (224 cols) rows into LDS ----
  for (int task = tid; task < (TW + GROWS) * 8; task += 256) {
    const bool isfl = task < TW * 8;
    const int local = isfl ? task : task - TW * 8;
    const int row = local >> 3;
    const int c4  = (local & 7) << 2;
    const int wup = isfl ? (w0 + row) : (w0 - 95 + row + IMG_W) % IMG_W;
    const int m   = wup >> 1;
    const int odd = wup & 1;
    int m0 = odd ? m : m - 1;
    int m1 = odd ? m + 1 : m;
    const float wh0 = odd ? 0.75f : 0.25f;
    const float wh1 = odd ? 0.25f : 0.75f;
    if (m0 < 0) m0 = 0;
    if (m1 > CWID - 1) m1 = CWID - 1;
    const int bb = isfl ? bz : bz + 2;
    const size_t rb0 = ((size_t)bb * CH + r0) * CWID;
    const size_t rb1 = ((size_t)bb * CH + r1) * CWID;
    const float4 a00 = *(const float4*)(Fc + (rb0 + m0) * 32 + c4);
    const float4 a01 = *(const float4*)(Fc + (rb0 + m1) * 32 + c4);
    const float4 a10 = *(const float4*)(Fc + (rb1 + m0) * 32 + c4);
    const float4 a11 = *(const float4*)(Fc + (rb1 + m1) * 32 + c4);
    float4 v;
    v.x = wv0 * (wh0 * a00.x + wh1 * a01.x) + wv1 * (wh0 * a10.x + wh1 * a11.x);
    v.y = wv0 * (wh0 * a00.y + wh1 * a01.y) + wv1 * (wh0 * a10.y + wh1 * a11.y);
    v.z = wv0 * (wh0 * a00.z + wh1 * a01.z) + wv1 * (wh0 * a10.z + wh1 * a11.z);
    v.w = wv0 * (wh0 * a00.w + wh1 * a01.w) + wv1 * (wh0 * a10.w + wh1 * a11.w);
    float* dst = (isfl ? flT : gT) + swz(row, c4);
    *(float4*)dst = v;
  }
  __syncthreads();

  // ---- Phase A: squared norms A[i], B[j] ----
  for (int task = tid; task < TW + GROWS; task += 256) {
    const bool isfl = task < TW;
    const int row = isfl ? task : task - TW;
    const float* buf = isfl ? flT : gT;
    float s = 0.f;
    #pragma unroll
    for (int c = 0; c < 32; c += 4) {
      const float4 v = *(const float4*)(buf + swz(row, c));
      s += v.x * v.x + v.y * v.y + v.z * v.z + v.w * v.w;
    }
    if (isfl) As[row] = s; else Bs[row] = s;
  }
  __syncthreads();

  // ---- Phase 2: banded correlation, 4i x 12k register tile per thread ----
  // ig = tid>>3 (32 groups), kg = tid&7: within a wave the 4 fl rows are shared by
  // 8 lanes each -> LDS broadcast; g rows are the streamed operand.
  const int i0 = (tid >> 3) * 4;
  const int kg = tid & 7;
  const int k0 = kg * 12;

  // Precomputed byte addresses: addr(row) = row*128 + ((row>>2)&7)<<4; per c-chunk
  // the swizzle is addr ^ (cc<<4)  (shift distributes over XOR; cc<<4 is a literal).
  int fla[4];
  #pragma unroll
  for (int ii = 0; ii < 4; ++ii) {
    const int row = i0 + ii;
    fla[ii] = row * 128 + (((row >> 2) & 7) << 4);
  }
  int ga[15];
  #pragma unroll
  for (int s = 0; s < 15; ++s) {
    const int row = i0 + k0 + s;
    ga[s] = row * 128 + (((row >> 2) & 7) << 4);
  }

  float acc[4][12];
  #pragma unroll
  for (int a = 0; a < 4; ++a)
    #pragma unroll
    for (int b = 0; b < 12; ++b) acc[a][b] = 0.f;

  const char* const flB = (const char*)flT;
  const char* const gB  = (const char*)gT;

  #pragma unroll
  for (int cc = 0; cc < 8; ++cc) {
    const int ccb = cc << 4;
    float4 fv[4];
    #pragma unroll
    for (int ii = 0; ii < 4; ++ii)
      fv[ii] = *(const float4*)(flB + (fla[ii] ^ ccb));
    #pragma unroll
    for (int s = 0; s < 15; ++s) {
      const float4 g = *(const float4*)(gB + (ga[s] ^ ccb));
      #pragma unroll
      for (int ii = 0; ii < 4; ++ii) {
        const int kk = s - ii;
        if (kk >= 0 && kk < 12) {
          acc[ii][kk] = fmaf(fv[ii].x, g.x, acc[ii][kk]);
          acc[ii][kk] = fmaf(fv[ii].y, g.y, acc[ii][kk]);
          acc[ii][kk] = fmaf(fv[ii].z, g.z, acc[ii][kk]);
          acc[ii][kk] = fmaf(fv[ii].w, g.w, acc[ii][kk]);
        }
      }
    }
  }
  __syncthreads();   // all flT reads done; flT becomes phase-3 scratch

  // finalize cost (in regs) + per-thread min/max
  #pragma unroll
  for (int ii = 0; ii < 4; ++ii) {
    const int i = i0 + ii;
    const float Ai = As[i];
    float mn = 3.0e38f, mx = -3.0e38f;
    #pragma unroll
    for (int kk = 0; kk < 12; ++kk) {
      const float cv = Ai + Bs[i + k0 + kk] - 2.f * acc[ii][kk];
      acc[ii][kk] = cv;
      mn = fminf(mn, cv);
      mx = fmaxf(mx, cv);
    }
    mnA[kg * TW + i] = mn;
    mxA[kg * TW + i] = mx;
  }
  __syncthreads();

  // ---- Phase 3a: reduce min/max over the 8 k-groups per pixel ----
  if (tid < TW) {
    float mn = mnA[tid], mx = mxA[tid];
    #pragma unroll
    for (int q = 1; q < 8; ++q) {
      mn = fminf(mn, mnA[q * TW + tid]);
      mx = fmaxf(mx, mxA[q * TW + tid]);
    }
    gmn[tid] = mn;
    gmx[tid] = mx;
  }
  __syncthreads();

  // ---- Phase 3b: partial softmax sums (cost still live in registers) ----
  #pragma unroll
  for (int ii = 0; ii < 4; ++ii) {
    const int i = i0 + ii;
    const float alpha = 177.0f / gmx[i];
    const float mn = gmn[i];
    float sw = 0.f, sdw = 0.f;
    #pragma unroll
    for (int kk = 0; kk < 12; ++kk) {
      const float wgt = __expf(alpha * (mn - acc[ii][kk]));  // in (0,1], stable
      sw += wgt;
      sdw += (float)(95 - (k0 + kk)) * wgt;                   // d = 95 - k
    }
    psw[kg * TW + i]  = sw;
    psdw[kg * TW + i] = sdw;
  }
  __syncthreads();

  // ---- Phase 3c: final reduce + soft-argmin write ----
  if (tid < TW) {
    float sw = 0.f, sdw = 0.f;
    #pragma unroll
    for (int q = 0; q < 8; ++q) {
      sw  += psw[q * TW + tid];
      sdw += psdw[q * TW + tid];
    }
    out[((size_t)bz * IMG_H + h) * IMG_W + w0 + tid] = sdw / sw;
  }
}

extern "C" void kernel_launch(void* const* d_in, const int* in_sizes, int n_in,
                              void* d_out, int out_size, void* d_ws, size_t ws_size,
                              hipStream_t stream) {
  (void)in_sizes; (void)n_in; (void)out_size; (void)ws_size;
  const float* xl   = (const float*)d_in[0];
  const float* xr   = (const float*)d_in[1];
  const float* Wt   = (const float*)d_in[2];
  const float* bias = (const float*)d_in[3];
  float* Fc  = (float*)d_ws;        // conv features [4,192,640,32] f32 = 62.9 MB
  float* out = (float*)d_out;       // [2,384,1280] f32

  hipLaunchKernelGGL(conv_relu_kernel, dim3(1920), dim3(256), 0, stream,
                     xl, xr, Wt, bias, Fc);
  hipLaunchKernelGGL(disparity_fused_kernel, dim3(IMG_W / TW, IMG_H, 2), dim3(256), 0, stream,
                     Fc, out);
}

// Round 3
// 182.434 us; speedup vs baseline: 1.4216x; 1.1534x over previous
//
#include <hip/hip_runtime.h>
#include <cstddef>

typedef __attribute__((ext_vector_type(8))) short short8;
typedef __attribute__((ext_vector_type(4))) float f32x4;
typedef __attribute__((ext_vector_type(4))) unsigned short u16x4;

#define FCH   32
#define CH    192
#define CWID  640
#define IMG_H 384
#define IMG_W 1280
#define TW    128
#define NDISP 96
#define RAWC  179    // 66 fl cols + 113 g cols
#define GR    224    // g rows staged

__device__ __forceinline__ unsigned short f2bf(float x) {
  unsigned u = __float_as_uint(x);
  u += 0x7FFFu + ((u >> 16) & 1u);
  return (unsigned short)(u >> 16);
}
__device__ __forceinline__ float bf2f(unsigned short b) {
  return __uint_as_float(((unsigned)b) << 16);
}

// ---------------- Kernel 1: 3x3 stride-2 SAME conv + bias + ReLU ----------------
__global__ __launch_bounds__(256)
void conv_relu_kernel(const float* __restrict__ xl, const float* __restrict__ xr,
                      const float* __restrict__ Wt, const float* __restrict__ bias,
                      float* __restrict__ Fc) {
  __shared__ float wl[864];
  __shared__ float bl[32];
  const int tid = threadIdx.x;
  for (int t = tid; t < 864; t += 256) wl[t] = Wt[t];
  if (tid < 32) bl[tid] = bias[tid];
  __syncthreads();

  const int g  = blockIdx.x * 256 + tid;
  const int ow = g % CWID;
  const int t2 = g / CWID;
  const int oh = t2 % CH;
  const int bb = t2 / CH;
  const float* src = (bb < 2) ? (xl + (size_t)bb * IMG_H * IMG_W * 3)
                              : (xr + (size_t)(bb - 2) * IMG_H * IMG_W * 3);
  float acc[32];
  #pragma unroll
  for (int c = 0; c < 32; ++c) acc[c] = bl[c];

  #pragma unroll
  for (int kh = 0; kh < 3; ++kh) {
    const int ir = oh * 2 + kh;
    if (ir >= IMG_H) continue;
    #pragma unroll
    for (int kw = 0; kw < 3; ++kw) {
      const int ic = ow * 2 + kw;
      if (ic >= IMG_W) continue;
      const float* px = src + ((size_t)ir * IMG_W + ic) * 3;
      #pragma unroll
      for (int ci = 0; ci < 3; ++ci) {
        const float v = px[ci];
        const float* wp = &wl[((kh * 3 + kw) * 3 + ci) * 32];
        #pragma unroll
        for (int c8 = 0; c8 < 8; ++c8) {
          const float4 w4 = *(const float4*)(wp + c8 * 4);
          acc[c8 * 4 + 0] = fmaf(v, w4.x, acc[c8 * 4 + 0]);
          acc[c8 * 4 + 1] = fmaf(v, w4.y, acc[c8 * 4 + 1]);
          acc[c8 * 4 + 2] = fmaf(v, w4.z, acc[c8 * 4 + 2]);
          acc[c8 * 4 + 3] = fmaf(v, w4.w, acc[c8 * 4 + 3]);
        }
      }
    }
  }
  float* dst = Fc + (size_t)g * 32;
  #pragma unroll
  for (int c8 = 0; c8 < 8; ++c8) {
    float4 o;
    o.x = fmaxf(acc[c8 * 4 + 0], 0.f);
    o.y = fmaxf(acc[c8 * 4 + 1], 0.f);
    o.z = fmaxf(acc[c8 * 4 + 2], 0.f);
    o.w = fmaxf(acc[c8 * 4 + 3], 0.f);
    *(float4*)(dst + c8 * 4) = o;
  }
}

// ------- Kernel 2: MFMA cost volume + soft-argmin -------
// Correlation = banded GEMM via mfma_f32_16x16x32_bf16 with hi/lo bf16 split.
// D[m=j(g-row), n=i(fl-row)] so each pixel's k-values live in 4 lanes (shfl reduce).
// 8 i-tiles x 7 diag j-tiles x 3 split MFMAs = 168 MFMAs/block.
__global__ __launch_bounds__(256)
void disparity_mfma_kernel(const float* __restrict__ Fc, float* __restrict__ out) {
  __shared__ float raw[RAWC * 16];            // 11.2 KB (half the channels at a time)
  __shared__ unsigned short flHi[8 * 512];    // 8 tiles [16][32] bf16
  __shared__ unsigned short flLo[8 * 512];
  __shared__ unsigned short gHi[14 * 512];    // 14 tiles
  __shared__ unsigned short gLo[14 * 512];
  __shared__ float As[TW];
  __shared__ float Bs[GR];

  const int tid = threadIdx.x;
  const int w0  = blockIdx.x * TW;
  const int h   = blockIdx.y;
  const int bz  = blockIdx.z;

  // vertical bilinear params (half-pixel, clamped)
  const int hk = h >> 1;
  int r0, r1; float wv0, wv1;
  if (h & 1) { r0 = hk; r1 = (hk + 1 > CH - 1) ? CH - 1 : hk + 1; wv0 = 0.75f; wv1 = 0.25f; }
  else       { r0 = (hk - 1 < 0) ? 0 : hk - 1; r1 = hk;           wv0 = 0.25f; wv1 = 0.75f; }

  const int vbaseL = (w0 >> 1) + 639;  // virtual col base, fl raw region (t 0..65)
  const int vbaseR = (w0 >> 1) + 592;  // g raw region (t 0..112 -> raw rows 66..178)

  float norm0 = 0.f, norm1 = 0.f;      // per-thread row norms accumulated across halves

  #pragma unroll
  for (int half = 0; half < 2; ++half) {
    // ---- Phase 0: raw staging (vertically pre-mixed), 4 channel-chunks ----
    for (int task = tid; task < RAWC * 4; task += 256) {
      const int t  = task >> 2;
      const int c4 = task & 3;
      const int c  = half * 4 + c4;
      const bool isfl = t < 66;
      const int col = (isfl ? (vbaseL + t) : (vbaseR + (t - 66))) % 640;
      const int bb  = isfl ? bz : bz + 2;
      const size_t rb0 = ((size_t)bb * CH + r0) * CWID + col;
      const size_t rb1 = ((size_t)bb * CH + r1) * CWID + col;
      const float4 a0 = *(const float4*)(Fc + rb0 * 32 + c * 4);
      const float4 a1 = *(const float4*)(Fc + rb1 * 32 + c * 4);
      float4 v;
      v.x = wv0 * a0.x + wv1 * a1.x;
      v.y = wv0 * a0.y + wv1 * a1.y;
      v.z = wv0 * a0.z + wv1 * a1.z;
      v.w = wv0 * a0.w + wv1 * a1.w;
      *(float4*)(raw + t * 16 + ((c4 ^ (t & 3)) << 2)) = v;
    }
    __syncthreads();

    // ---- Phase 1: horizontal bilinear + hi/lo bf16 split + norm partials ----
    for (int row = tid; row < TW + GR; row += 256) {
      const bool isfl = row < TW;
      const int r  = isfl ? row : row - TW;           // local row in region
      const int uv = isfl ? (w0 + r) : (w0 - 95 + r); // virtual up-col
      const int uact = uv < 0 ? uv + IMG_W : (uv >= IMG_W ? uv - IMG_W : uv);
      const int up = uv + IMG_W;                      // positive, same parity
      int vm0, vm1; float wh0, wh1;
      if (up & 1) { vm0 = (up - 1) >> 1; vm1 = vm0 + 1; wh0 = 0.75f; wh1 = 0.25f; }
      else        { vm1 = up >> 1;       vm0 = vm1 - 1; wh0 = 0.25f; wh1 = 0.75f; }
      int t0 = isfl ? (vm0 - vbaseL) : (vm0 - vbaseR + 66);
      int t1 = isfl ? (vm1 - vbaseL) : (vm1 - vbaseR + 66);
      if (uact == 0)         t0 = t1;   // left-edge clamp: both taps = col 0
      if (uact == IMG_W - 1) t1 = t0;   // right-edge clamp
      const int k0s = t0 & 3, k1s = t1 & 3;
      const int rr  = r & 15;
      const int gsw = (rr >> 1) & 3;    // per-row slot swizzle for tiles
      unsigned short* hiB = (isfl ? flHi : gHi) + (r >> 4) * 512;
      unsigned short* loB = (isfl ? flLo : gLo) + (r >> 4) * 512;
      float nacc = 0.f;
      #pragma unroll
      for (int c4 = 0; c4 < 4; ++c4) {
        const int c = half * 4 + c4;
        const float4 a = *(const float4*)(raw + t0 * 16 + ((c4 ^ k0s) << 2));
        const float4 b = *(const float4*)(raw + t1 * 16 + ((c4 ^ k1s) << 2));
        float4 v;
        v.x = wh0 * a.x + wh1 * b.x;
        v.y = wh0 * a.y + wh1 * b.y;
        v.z = wh0 * a.z + wh1 * b.z;
        v.w = wh0 * a.w + wh1 * b.w;
        nacc += v.x * v.x + v.y * v.y + v.z * v.z + v.w * v.w;
        u16x4 hv, lv;
        hv.x = f2bf(v.x); lv.x = f2bf(v.x - bf2f(hv.x));
        hv.y = f2bf(v.y); lv.y = f2bf(v.y - bf2f(hv.y));
        hv.z = f2bf(v.z); lv.z = f2bf(v.z - bf2f(hv.z));
        hv.w = f2bf(v.w); lv.w = f2bf(v.w - bf2f(hv.w));
        const int eoff = rr * 32 + (((c >> 1) ^ gsw) * 8) + ((c & 1) * 4);
        *(u16x4*)(hiB + eoff) = hv;
        *(u16x4*)(loB + eoff) = lv;
      }
      if (row == tid) norm0 += nacc; else norm1 += nacc;
    }
    __syncthreads();
  }
  // store norms (after both halves)
  {
    const int row = tid;
    if (row < TW) As[row] = norm0; else Bs[row - TW] = norm0;
    const int row2 = tid + 256;
    if (row2 < TW + GR) Bs[row2 - TW] = norm1;
  }
  __syncthreads();

  // ---- Phase 2: MFMA band + per-pixel soft-argmin ----
  const int lane = tid & 63;
  const int wid  = tid >> 6;
  const int n  = lane & 15;   // i within tile (C col) and frag row
  const int gq = lane >> 4;   // k-slice for frags; C row group
  const int foff = n * 32 + ((gq ^ ((n >> 1) & 3)) * 8);  // bf16-element offset

  #pragma unroll
  for (int pp = 0; pp < 2; ++pp) {
    const int p = wid * 2 + pp;          // i-tile index 0..7
    const short8 bhi = *(const short8*)((const short*)flHi + p * 512 + foff);
    const short8 blo = *(const short8*)((const short*)flLo + p * 512 + foff);
    f32x4 acc[7];
    #pragma unroll
    for (int dq = 0; dq < 7; ++dq) {
      const int q = p + dq;              // j-tile 0..13
      const short8 ahi = *(const short8*)((const short*)gHi + q * 512 + foff);
      const short8 alo = *(const short8*)((const short*)gLo + q * 512 + foff);
      f32x4 z = {0.f, 0.f, 0.f, 0.f};
      z = __builtin_amdgcn_mfma_f32_16x16x32_bf16(alo, bhi, z, 0, 0, 0);
      z = __builtin_amdgcn_mfma_f32_16x16x32_bf16(ahi, blo, z, 0, 0, 0);
      z = __builtin_amdgcn_mfma_f32_16x16x32_bf16(ahi, bhi, z, 0, 0, 0);
      acc[dq] = z;
    }

    // epilogue: cost = As[i] + Bs[j] - 2*corr; mask k outside [0,95]
    const float Ai = As[p * 16 + n];
    float cv[7][4];
    float mn = 3.0e38f, mx = -3.0e38f;
    #pragma unroll
    for (int dq = 0; dq < 7; ++dq) {
      #pragma unroll
      for (int rg = 0; rg < 4; ++rg) {
        const int m = gq * 4 + rg;
        const int j = (p + dq) * 16 + m;
        const int k = dq * 16 + m - n;
        const float cc = Ai + Bs[j] - 2.f * acc[dq][rg];
        cv[dq][rg] = cc;
        if (k >= 0 && k <= 95) { mn = fminf(mn, cc); mx = fmaxf(mx, cc); }
      }
    }
    mn = fminf(mn, __shfl_xor(mn, 16, 64));
    mn = fminf(mn, __shfl_xor(mn, 32, 64));
    mx = fmaxf(mx, __shfl_xor(mx, 16, 64));
    mx = fmaxf(mx, __shfl_xor(mx, 32, 64));

    const float alpha = 177.0f / mx;
    float sw = 0.f, sdw = 0.f;
    #pragma unroll
    for (int dq = 0; dq < 7; ++dq) {
      #pragma unroll
      for (int rg = 0; rg < 4; ++rg) {
        const int m = gq * 4 + rg;
        const int k = dq * 16 + m - n;
        const bool valid = (k >= 0 && k <= 95);
        const float arg = valid ? alpha * (mn - cv[dq][rg]) : -100.f;
        const float wgt = __expf(arg);   // in (0,1], ~0 for masked
        sw  += wgt;
        sdw += (float)(95 - k) * wgt;    // d = 95 - k
      }
    }
    sw  += __shfl_xor(sw, 16, 64);  sw  += __shfl_xor(sw, 32, 64);
    sdw += __shfl_xor(sdw, 16, 64); sdw += __shfl_xor(sdw, 32, 64);
    if (gq == 0)
      out[((size_t)bz * IMG_H + h) * IMG_W + w0 + p * 16 + n] = sdw / sw;
  }
}

extern "C" void kernel_launch(void* const* d_in, const int* in_sizes, int n_in,
                              void* d_out, int out_size, void* d_ws, size_t ws_size,
                              hipStream_t stream) {
  (void)in_sizes; (void)n_in; (void)out_size; (void)ws_size;
  const float* xl   = (const float*)d_in[0];
  const float* xr   = (const float*)d_in[1];
  const float* Wt   = (const float*)d_in[2];
  const float* bias = (const float*)d_in[3];
  float* Fc  = (float*)d_ws;        // conv features [4,192,640,32] f32 = 62.9 MB
  float* out = (float*)d_out;       // [2,384,1280] f32

  hipLaunchKernelGGL(conv_relu_kernel, dim3(1920), dim3(256), 0, stream,
                     xl, xr, Wt, bias, Fc);
  hipLaunchKernelGGL(disparity_mfma_kernel, dim3(IMG_W / TW, IMG_H, 2), dim3(256), 0, stream,
                     Fc, out);
}

// Round 4
// 99.254 us; speedup vs baseline: 2.6130x; 1.8380x over previous
//
#include <hip/hip_runtime.h>
#include <cstddef>

typedef _Float16 h2    __attribute__((ext_vector_type(2)));
typedef _Float16 half8 __attribute__((ext_vector_type(8)));
typedef float    f32x4 __attribute__((ext_vector_type(4)));

#define CH    192
#define CWID  640
#define IMG_H 384
#define IMG_W 1280
#define TW    128
#define GR    224    // g rows staged
#define RAWC  179    // 66 fl cols + 113 g cols

// ---------------- Kernel 1: 3x3 stride-2 SAME conv + bias + ReLU -> f16 ----------------
__global__ __launch_bounds__(256)
void conv_relu_kernel(const float* __restrict__ xl, const float* __restrict__ xr,
                      const float* __restrict__ Wt, const float* __restrict__ bias,
                      _Float16* __restrict__ Fc) {
  __shared__ float wl[864];
  __shared__ float bl[32];
  const int tid = threadIdx.x;
  for (int t = tid; t < 864; t += 256) wl[t] = Wt[t];
  if (tid < 32) bl[tid] = bias[tid];
  __syncthreads();

  const int g  = blockIdx.x * 256 + tid;   // [0, 4*192*640)
  const int ow = g % CWID;
  const int t2 = g / CWID;
  const int oh = t2 % CH;
  const int bb = t2 / CH;
  const float* src = (bb < 2) ? (xl + (size_t)bb * IMG_H * IMG_W * 3)
                              : (xr + (size_t)(bb - 2) * IMG_H * IMG_W * 3);
  float acc[32];
  #pragma unroll
  for (int c = 0; c < 32; ++c) acc[c] = bl[c];

  #pragma unroll
  for (int kh = 0; kh < 3; ++kh) {
    const int ir = oh * 2 + kh;
    if (ir >= IMG_H) continue;
    #pragma unroll
    for (int kw = 0; kw < 3; ++kw) {
      const int ic = ow * 2 + kw;
      if (ic >= IMG_W) continue;
      const float* px = src + ((size_t)ir * IMG_W + ic) * 3;
      #pragma unroll
      for (int ci = 0; ci < 3; ++ci) {
        const float v = px[ci];
        const float* wp = &wl[((kh * 3 + kw) * 3 + ci) * 32];
        #pragma unroll
        for (int c8 = 0; c8 < 8; ++c8) {
          const float4 w4 = *(const float4*)(wp + c8 * 4);
          acc[c8 * 4 + 0] = fmaf(v, w4.x, acc[c8 * 4 + 0]);
          acc[c8 * 4 + 1] = fmaf(v, w4.y, acc[c8 * 4 + 1]);
          acc[c8 * 4 + 2] = fmaf(v, w4.z, acc[c8 * 4 + 2]);
          acc[c8 * 4 + 3] = fmaf(v, w4.w, acc[c8 * 4 + 3]);
        }
      }
    }
  }
  // relu + pack to f16 (RNE via scalar cvt), 4x 16B stores
  _Float16 hv[32];
  #pragma unroll
  for (int c = 0; c < 32; ++c) hv[c] = (_Float16)fmaxf(acc[c], 0.f);
  half8* dst = (half8*)(Fc + (size_t)g * 32);
  #pragma unroll
  for (int q = 0; q < 4; ++q) {
    half8 o;
    #pragma unroll
    for (int e = 0; e < 8; ++e) o[e] = hv[q * 8 + e];
    dst[q] = o;
  }
}

// ------- Kernel 2: f16 MFMA cost volume + soft-argmin -------
// corr = banded GEMM via one mfma_f32_16x16x32_f16 per tile pair.
// Norms computed from the SAME f16 values -> cost = ||v16-g16||^2 (consistent),
// so error ~ 2*sqrt(cost)*eps, vanishing near the softmax peak.
__global__ __launch_bounds__(256, 4)
void disparity_mfma_kernel(const _Float16* __restrict__ Fc, float* __restrict__ out) {
  __shared__ alignas(16) _Float16 raw[RAWC * 32];   // 11.2 KB, vertically blended
  __shared__ alignas(16) _Float16 flH[8 * 512];     // 8 tiles [16][32] f16, 8 KB
  __shared__ alignas(16) _Float16 gH[14 * 512];     // 14 tiles, 14 KB
  __shared__ alignas(16) float As[TW];
  __shared__ alignas(16) float Bs[GR];

  const int tid = threadIdx.x;
  const int w0  = blockIdx.x * TW;
  const int h   = blockIdx.y;
  const int bz  = blockIdx.z;

  // vertical bilinear params (half-pixel, clamped)
  const int hk = h >> 1;
  int r0, r1; float wv0;
  if (h & 1) { r0 = hk; r1 = (hk + 1 > CH - 1) ? CH - 1 : hk + 1; wv0 = 0.75f; }
  else       { r0 = (hk - 1 < 0) ? 0 : hk - 1; r1 = hk;           wv0 = 0.25f; }
  const _Float16 w0h = (_Float16)wv0;
  const _Float16 w1h = (_Float16)(1.0f - wv0);
  const half8 w0v = (half8)w0h;
  const half8 w1v = (half8)w1h;

  const int vbaseL = (w0 >> 1) + 639;  // fl raw region (t 0..65)
  const int vbaseR = (w0 >> 1) + 592;  // g raw region (t 66..178)

  char* const rawB = (char*)raw;

  // ---- Phase 0: stage + vertical blend (f16 pk math), 16B chunks ----
  for (int task = tid; task < RAWC * 4; task += 256) {
    const int t   = task >> 2;
    const int c16 = task & 3;
    const bool isfl = t < 66;
    const int col = (isfl ? (vbaseL + t) : (vbaseR + (t - 66))) % 640;
    const int bb  = isfl ? bz : bz + 2;
    const half8 a0 = *(const half8*)(Fc + (((size_t)bb * CH + r0) * CWID + col) * 32 + c16 * 8);
    const half8 a1 = *(const half8*)(Fc + (((size_t)bb * CH + r1) * CWID + col) * 32 + c16 * 8);
    const half8 v = a0 * w0v + a1 * w1v;
    *(half8*)(rawB + t * 64 + ((c16 ^ (t & 3)) << 4)) = v;
  }
  __syncthreads();

  // ---- Phase 1: horizontal blend (f16) + tiles + norms (fdot2 on same f16) ----
  for (int row = tid; row < TW + GR; row += 256) {
    const bool isfl = row < TW;
    const int r  = isfl ? row : row - TW;
    const int uv = isfl ? (w0 + r) : (w0 - 95 + r);
    const int uact = uv < 0 ? uv + IMG_W : (uv >= IMG_W ? uv - IMG_W : uv);
    const int up = uv + IMG_W;                       // positive, same parity
    int vm0, vm1; float whf;
    if (up & 1) { vm0 = (up - 1) >> 1; vm1 = vm0 + 1; whf = 0.75f; }
    else        { vm1 = up >> 1;       vm0 = vm1 - 1; whf = 0.25f; }
    int t0 = isfl ? (vm0 - vbaseL) : (vm0 - vbaseR + 66);
    int t1 = isfl ? (vm1 - vbaseL) : (vm1 - vbaseR + 66);
    if (uact == 0)         t0 = t1;   // left-edge clamp
    if (uact == IMG_W - 1) t1 = t0;   // right-edge clamp
    const half8 h0v = (half8)(_Float16)whf;
    const half8 h1v = (half8)(_Float16)(1.0f - whf);
    const char* r0p = rawB + t0 * 64;
    const char* r1p = rawB + t1 * 64;
    const int k0s = t0 & 3, k1s = t1 & 3;
    const int rr  = r & 15;
    char* dstB = (char*)(isfl ? flH : gH) + (r >> 4) * 1024 + rr * 64;
    float s = 0.f;
    #pragma unroll
    for (int c16 = 0; c16 < 4; ++c16) {
      const half8 a = *(const half8*)(r0p + ((c16 ^ k0s) << 4));
      const half8 b = *(const half8*)(r1p + ((c16 ^ k1s) << 4));
      const half8 v = a * h0v + b * h1v;
      #pragma unroll
      for (int e = 0; e < 4; ++e) {
        h2 pe = {v[2 * e], v[2 * e + 1]};
#if __has_builtin(__builtin_amdgcn_fdot2)
        s = __builtin_amdgcn_fdot2(pe, pe, s, false);
#else
        s += (float)pe[0] * (float)pe[0] + (float)pe[1] * (float)pe[1];
#endif
      }
      *(half8*)(dstB + ((c16 ^ (rr & 3)) << 4)) = v;
    }
    if (isfl) As[r] = s; else Bs[r] = s;
  }
  __syncthreads();

  // ---- Phase 2: MFMA band + per-pixel soft-argmin ----
  const int lane = tid & 63;
  const int wid  = tid >> 6;
  const int n  = lane & 15;   // fl row within tile (C col)
  const int gq = lane >> 4;   // k-slice / C row group
  const int foffB = n * 64 + ((gq ^ (n & 3)) << 4);

  #pragma unroll
  for (int pp = 0; pp < 2; ++pp) {
    const int p = wid * 2 + pp;          // i-tile 0..7
    const half8 bfrag = *(const half8*)((const char*)flH + p * 1024 + foffB);
    f32x4 acc[7];
    #pragma unroll
    for (int dq = 0; dq < 7; ++dq) {
      const half8 afrag = *(const half8*)((const char*)gH + (p + dq) * 1024 + foffB);
      f32x4 z = {0.f, 0.f, 0.f, 0.f};
      acc[dq] = __builtin_amdgcn_mfma_f32_16x16x32_f16(afrag, bfrag, z, 0, 0, 0);
    }

    // pass 1: cost + min/max (band masks only at dq 0 and 6)
    const float Ai = As[p * 16 + n];
    float cv[7][4];
    float mn = 3.0e38f, mx = -3.0e38f;
    #pragma unroll
    for (int dq = 0; dq < 7; ++dq) {
      const f32x4 b4 = *(const f32x4*)(&Bs[(p + dq) * 16 + gq * 4]);
      #pragma unroll
      for (int rg = 0; rg < 4; ++rg) {
        const int m = gq * 4 + rg;
        const float cc = fmaf(-2.f, acc[dq][rg], Ai + b4[rg]);
        cv[dq][rg] = cc;
        const bool valid = (dq != 0 || m >= n) && (dq != 6 || m < n);
        mn = fminf(mn, valid ? cc : 3.0e38f);
        mx = fmaxf(mx, valid ? cc : -3.0e38f);
      }
    }
    mn = fminf(mn, __shfl_xor(mn, 16, 64));
    mn = fminf(mn, __shfl_xor(mn, 32, 64));
    mx = fmaxf(mx, __shfl_xor(mx, 16, 64));
    mx = fmaxf(mx, __shfl_xor(mx, 32, 64));

    // pass 2: softmax accumulation, log2e folded into alpha
    const float alpha = 177.0f * 1.4426950408889634f / mx;
    const float na   = -alpha;
    const float base = alpha * mn;
    float sw = 0.f, sdw = 0.f;
    #pragma unroll
    for (int dq = 0; dq < 7; ++dq) {
      #pragma unroll
      for (int rg = 0; rg < 4; ++rg) {
        const int m = gq * 4 + rg;
        const bool valid = (dq != 0 || m >= n) && (dq != 6 || m < n);
        float wgt = exp2f(fmaf(na, cv[dq][rg], base));
        wgt = valid ? wgt : 0.f;
        sw += wgt;
        const float kf = (float)(95 - (dq * 16 + m - n));   // d = 95 - k
        sdw = fmaf(kf, wgt, sdw);
      }
    }
    sw  += __shfl_xor(sw, 16, 64);  sw  += __shfl_xor(sw, 32, 64);
    sdw += __shfl_xor(sdw, 16, 64); sdw += __shfl_xor(sdw, 32, 64);
    if (gq == 0)
      out[((size_t)bz * IMG_H + h) * IMG_W + w0 + p * 16 + n] = sdw / sw;
  }
}

extern "C" void kernel_launch(void* const* d_in, const int* in_sizes, int n_in,
                              void* d_out, int out_size, void* d_ws, size_t ws_size,
                              hipStream_t stream) {
  (void)in_sizes; (void)n_in; (void)out_size; (void)ws_size;
  const float* xl   = (const float*)d_in[0];
  const float* xr   = (const float*)d_in[1];
  const float* Wt   = (const float*)d_in[2];
  const float* bias = (const float*)d_in[3];
  _Float16* Fc = (_Float16*)d_ws;   // conv features [4,192,640,32] f16 = 31.5 MB
  float* out = (float*)d_out;       // [2,384,1280] f32

  hipLaunchKernelGGL(conv_relu_kernel, dim3(1920), dim3(256), 0, stream,
                     xl, xr, Wt, bias, Fc);
  hipLaunchKernelGGL(disparity_mfma_kernel, dim3(IMG_W / TW, IMG_H, 2), dim3(256), 0, stream,
                     Fc, out);
}